// Round 1
// baseline (151.939 us; speedup 1.0000x reference)
//
#include <hip/hip_runtime.h>
#include <hip/hip_bf16.h>
#include <math.h>

#define NQ   10
#define DIM  1024     // 2^NQ
#define NL   4
#define INF  512
#define OUTF 64

// ---------------------------------------------------------------------------
// Kernel 1: h = relu(x @ W_pre^T + b_pre)
// x: [M, K] row-major, W: [N, K] row-major, H: [M, N]
// M=4096, K=512, N=1024. Tile 64x64x16, 256 threads, 4x4 acc per thread.
// ---------------------------------------------------------------------------
__global__ __launch_bounds__(256) void gemm_relu_kernel(
    const float* __restrict__ X, const float* __restrict__ W,
    const float* __restrict__ bias, float* __restrict__ H)
{
    constexpr int GM = 64, GN = 64, GK = 16;
    __shared__ __align__(16) float As[GK][GM + 4];
    __shared__ __align__(16) float Bs[GK][GN + 4];

    const int tid = threadIdx.x;
    const int tx = tid & 15;        // 0..15
    const int ty = tid >> 4;        // 0..15
    const int lr = tid >> 2;        // 0..63 tile row for staging
    const int lk = (tid & 3) << 2;  // k offset 0,4,8,12

    const float* xg = X + (size_t)(blockIdx.x * GM + lr) * INF;
    const float* wg = W + (size_t)(blockIdx.y * GN + lr) * INF;

    float acc[4][4] = {};

    for (int k0 = 0; k0 < INF; k0 += GK) {
        float4 av = *reinterpret_cast<const float4*>(xg + k0 + lk);
        float4 bv = *reinterpret_cast<const float4*>(wg + k0 + lk);
        __syncthreads();
        As[lk + 0][lr] = av.x; As[lk + 1][lr] = av.y;
        As[lk + 2][lr] = av.z; As[lk + 3][lr] = av.w;
        Bs[lk + 0][lr] = bv.x; Bs[lk + 1][lr] = bv.y;
        Bs[lk + 2][lr] = bv.z; Bs[lk + 3][lr] = bv.w;
        __syncthreads();
#pragma unroll
        for (int kk = 0; kk < GK; ++kk) {
            float4 a = *reinterpret_cast<const float4*>(&As[kk][ty << 2]);
            float4 b = *reinterpret_cast<const float4*>(&Bs[kk][tx << 2]);
            float ar[4] = {a.x, a.y, a.z, a.w};
            float br[4] = {b.x, b.y, b.z, b.w};
#pragma unroll
            for (int i = 0; i < 4; ++i)
#pragma unroll
                for (int j = 0; j < 4; ++j)
                    acc[i][j] = fmaf(ar[i], br[j], acc[i][j]);
        }
    }

    const int gm = blockIdx.x * GM + (ty << 2);
    const int gn = blockIdx.y * GN + (tx << 2);
    float bb0 = bias[gn + 0], bb1 = bias[gn + 1], bb2 = bias[gn + 2], bb3 = bias[gn + 3];
#pragma unroll
    for (int i = 0; i < 4; ++i) {
        float4 o;
        o.x = fmaxf(acc[i][0] + bb0, 0.f);
        o.y = fmaxf(acc[i][1] + bb1, 0.f);
        o.z = fmaxf(acc[i][2] + bb2, 0.f);
        o.w = fmaxf(acc[i][3] + bb3, 0.f);
        *reinterpret_cast<float4*>(&H[(size_t)(gm + i) * DIM + gn]) = o;
    }
}

// ---------------------------------------------------------------------------
// Kernel 2: per batch row — amplitude embed (normalize), 4 layers of
// (10 Rot gates + CNOT ring permutation), PauliZ expvals, post-GEMM fused.
// One 256-thread block per row. State in LDS (re/im split).
// Wire w <-> bit (9-w) (MSB-first from the (2,)*10 reshape).
// ---------------------------------------------------------------------------
__global__ __launch_bounds__(256) void quantum_kernel(
    const float* __restrict__ Hbuf, const float* __restrict__ qw,
    const float* __restrict__ W_post, const float* __restrict__ b_post,
    float* __restrict__ out)
{
    __shared__ float sre[DIM];
    __shared__ float sim[DIM];
    __shared__ float su[NL * NQ][8];
    __shared__ float red[4];
    __shared__ float zred[4][NQ];
    __shared__ float zsh[NQ];

    const int tid = threadIdx.x;
    const int b = blockIdx.x;

    // --- gate unitaries: Rot(phi,theta,omega) = RZ(omega) RY(theta) RZ(phi)
    if (tid < NL * NQ) {
        float phi = qw[tid * 3 + 0], theta = qw[tid * 3 + 1], omega = qw[tid * 3 + 2];
        float st, ct; sincosf(0.5f * theta, &st, &ct);
        float spm, cpm; sincosf(0.5f * (phi - omega), &spm, &cpm);
        float spp, cpp; sincosf(0.5f * (phi + omega), &spp, &cpp);
        su[tid][0] =  cpp * ct; su[tid][1] = -spp * ct;   // U00 = e^{-i(phi+omega)/2} c
        su[tid][2] = -cpm * st; su[tid][3] = -spm * st;   // U01 = -e^{+i(phi-omega)/2} s
        su[tid][4] =  cpm * st; su[tid][5] = -spm * st;   // U10 = e^{-i(phi-omega)/2} s
        su[tid][6] =  cpp * ct; su[tid][7] =  spp * ct;   // U11 = e^{+i(phi+omega)/2} c
    }

    // --- amplitude embedding with normalization
    const float* hr = Hbuf + (size_t)b * DIM;
    float4 hv = *reinterpret_cast<const float4*>(hr + (tid << 2));
    float local = hv.x * hv.x + hv.y * hv.y + hv.z * hv.z + hv.w * hv.w;
#pragma unroll
    for (int off = 32; off > 0; off >>= 1) local += __shfl_down(local, off, 64);
    if ((tid & 63) == 0) red[tid >> 6] = local;
    __syncthreads();
    const float rn = rsqrtf(red[0] + red[1] + red[2] + red[3]);
    sre[(tid << 2) + 0] = hv.x * rn; sim[(tid << 2) + 0] = 0.f;
    sre[(tid << 2) + 1] = hv.y * rn; sim[(tid << 2) + 1] = 0.f;
    sre[(tid << 2) + 2] = hv.z * rn; sim[(tid << 2) + 2] = 0.f;
    sre[(tid << 2) + 3] = hv.w * rn; sim[(tid << 2) + 3] = 0.f;

    // --- layers
    int lw = 0;
    for (int l = 0; l < NL; ++l) {
        for (int w = 0; w < NQ; ++w, ++lw) {
            __syncthreads();
            const float u00r = su[lw][0], u00i = su[lw][1];
            const float u01r = su[lw][2], u01i = su[lw][3];
            const float u10r = su[lw][4], u10i = su[lw][5];
            const float u11r = su[lw][6], u11i = su[lw][7];
            const int bb = 9 - w;
            const int mask = 1 << bb;
#pragma unroll
            for (int p2 = 0; p2 < 2; ++p2) {
                const int p = tid + (p2 << 8);                       // pair id 0..511
                const int i0 = ((p >> bb) << (bb + 1)) | (p & (mask - 1));
                const int i1 = i0 | mask;
                const float a0r = sre[i0], a0i = sim[i0];
                const float a1r = sre[i1], a1i = sim[i1];
                sre[i0] = u00r * a0r - u00i * a0i + u01r * a1r - u01i * a1i;
                sim[i0] = u00r * a0i + u00i * a0r + u01r * a1i + u01i * a1r;
                sre[i1] = u10r * a0r - u10i * a0i + u11r * a1r - u11i * a1i;
                sim[i1] = u10r * a0i + u10i * a0r + u11r * a1i + u11i * a1r;
            }
        }
        // --- CNOT ring: composed permutation. psi_out[i] = psi[f_0(f_1(...f_9(i)))]
        const int r = (l % (NQ - 1)) + 1;
        __syncthreads();
        float vr[4], vi[4];
#pragma unroll
        for (int k = 0; k < 4; ++k) {
            const int i = tid + (k << 8);
            int j = i;
#pragma unroll
            for (int w2 = NQ - 1; w2 >= 0; --w2) {
                const int cb = 9 - w2;
                const int tb = 9 - ((w2 + r) % NQ);
                j ^= ((j >> cb) & 1) << tb;
            }
            vr[k] = sre[j]; vi[k] = sim[j];
        }
        __syncthreads();
#pragma unroll
        for (int k = 0; k < 4; ++k) { sre[tid + (k << 8)] = vr[k]; sim[tid + (k << 8)] = vi[k]; }
    }

    // --- PauliZ expectations
    __syncthreads();
    float zloc[NQ];
#pragma unroll
    for (int w = 0; w < NQ; ++w) zloc[w] = 0.f;
#pragma unroll
    for (int k = 0; k < 4; ++k) {
        const int i = tid + (k << 8);
        const float p = sre[i] * sre[i] + sim[i] * sim[i];
#pragma unroll
        for (int w = 0; w < NQ; ++w)
            zloc[w] += ((i >> (9 - w)) & 1) ? -p : p;
    }
#pragma unroll
    for (int w = 0; w < NQ; ++w)
#pragma unroll
        for (int off = 32; off > 0; off >>= 1)
            zloc[w] += __shfl_down(zloc[w], off, 64);
    if ((tid & 63) == 0) {
#pragma unroll
        for (int w = 0; w < NQ; ++w) zred[tid >> 6][w] = zloc[w];
    }
    __syncthreads();
    if (tid < NQ) zsh[tid] = zred[0][tid] + zred[1][tid] + zred[2][tid] + zred[3][tid];
    __syncthreads();

    // --- post-GEMM: out = z @ W_post^T + b_post (64 outputs)
    if (tid < OUTF) {
        float o = b_post[tid];
#pragma unroll
        for (int w = 0; w < NQ; ++w) o = fmaf(zsh[w], W_post[tid * NQ + w], o);
        out[(size_t)b * OUTF + tid] = o;
    }
}

extern "C" void kernel_launch(void* const* d_in, const int* in_sizes, int n_in,
                              void* d_out, int out_size, void* d_ws, size_t ws_size,
                              hipStream_t stream) {
    const float* x      = (const float*)d_in[0];
    const float* W_pre  = (const float*)d_in[1];
    const float* b_pre  = (const float*)d_in[2];
    const float* qw     = (const float*)d_in[3];
    const float* W_post = (const float*)d_in[4];
    const float* b_post = (const float*)d_in[5];
    float* out = (float*)d_out;
    float* h   = (float*)d_ws;   // 4096*1024 f32 = 16 MB scratch

    const int M = 4096;
    dim3 g1(M / 64, DIM / 64);
    gemm_relu_kernel<<<g1, 256, 0, stream>>>(x, W_pre, b_pre, h);
    quantum_kernel<<<M, 256, 0, stream>>>(h, qw, W_post, b_post, out);
}

// Round 2
// 117.692 us; speedup vs baseline: 1.2910x; 1.2910x over previous
//
#include <hip/hip_runtime.h>
#include <hip/hip_bf16.h>
#include <math.h>

#define NQ   10
#define DIM  1024     // 2^NQ
#define NL   4
#define INF  512
#define OUTF 64

// ---------------------------------------------------------------------------
// Kernel 1: h = relu(x @ W_pre^T + b_pre)   (unchanged from round 1)
// ---------------------------------------------------------------------------
__global__ __launch_bounds__(256) void gemm_relu_kernel(
    const float* __restrict__ X, const float* __restrict__ W,
    const float* __restrict__ bias, float* __restrict__ H)
{
    constexpr int GM = 64, GN = 64, GK = 16;
    __shared__ __align__(16) float As[GK][GM + 4];
    __shared__ __align__(16) float Bs[GK][GN + 4];

    const int tid = threadIdx.x;
    const int tx = tid & 15;
    const int ty = tid >> 4;
    const int lr = tid >> 2;
    const int lk = (tid & 3) << 2;

    const float* xg = X + (size_t)(blockIdx.x * GM + lr) * INF;
    const float* wg = W + (size_t)(blockIdx.y * GN + lr) * INF;

    float acc[4][4] = {};

    for (int k0 = 0; k0 < INF; k0 += GK) {
        float4 av = *reinterpret_cast<const float4*>(xg + k0 + lk);
        float4 bv = *reinterpret_cast<const float4*>(wg + k0 + lk);
        __syncthreads();
        As[lk + 0][lr] = av.x; As[lk + 1][lr] = av.y;
        As[lk + 2][lr] = av.z; As[lk + 3][lr] = av.w;
        Bs[lk + 0][lr] = bv.x; Bs[lk + 1][lr] = bv.y;
        Bs[lk + 2][lr] = bv.z; Bs[lk + 3][lr] = bv.w;
        __syncthreads();
#pragma unroll
        for (int kk = 0; kk < GK; ++kk) {
            float4 a = *reinterpret_cast<const float4*>(&As[kk][ty << 2]);
            float4 b = *reinterpret_cast<const float4*>(&Bs[kk][tx << 2]);
            float ar[4] = {a.x, a.y, a.z, a.w};
            float br[4] = {b.x, b.y, b.z, b.w};
#pragma unroll
            for (int i = 0; i < 4; ++i)
#pragma unroll
                for (int j = 0; j < 4; ++j)
                    acc[i][j] = fmaf(ar[i], br[j], acc[i][j]);
        }
    }

    const int gm = blockIdx.x * GM + (ty << 2);
    const int gn = blockIdx.y * GN + (tx << 2);
    float bb0 = bias[gn + 0], bb1 = bias[gn + 1], bb2 = bias[gn + 2], bb3 = bias[gn + 3];
#pragma unroll
    for (int i = 0; i < 4; ++i) {
        float4 o;
        o.x = fmaxf(acc[i][0] + bb0, 0.f);
        o.y = fmaxf(acc[i][1] + bb1, 0.f);
        o.z = fmaxf(acc[i][2] + bb2, 0.f);
        o.w = fmaxf(acc[i][3] + bb3, 0.f);
        *reinterpret_cast<float4*>(&H[(size_t)(gm + i) * DIM + gn]) = o;
    }
}

// ---------------------------------------------------------------------------
// Kernel 2: one wave (64 threads) per batch row; 16 amps/thread in registers.
// Global amp index i = (lane<<4) | k.  Wire w acts on bit (9-w):
//   wires 0..5 -> lane bits 5..0  -> __shfl_xor exchange
//   wires 6..9 -> k bits 3..0     -> register-local
// CNOT ring = GF(2)-linear permutation: perm(lane<<4|k)=perm(lane<<4)^perm(k);
// applied via one swizzled LDS round-trip per layer.
// ---------------------------------------------------------------------------
__device__ __forceinline__ int perm_chain(int j, int r) {
#pragma unroll
    for (int w2 = NQ - 1; w2 >= 0; --w2) {
        const int cb = 9 - w2;
        const int tb = 9 - ((w2 + r) % NQ);
        j ^= ((j >> cb) & 1) << tb;
    }
    return j;
}

__global__ __launch_bounds__(64) void quantum_kernel(
    const float* __restrict__ Hbuf, const float* __restrict__ qw,
    const float* __restrict__ W_post, const float* __restrict__ b_post,
    float* __restrict__ out)
{
    __shared__ __align__(16) float su[NL * NQ][8];
    __shared__ float sre[DIM];
    __shared__ float sim[DIM];

    const int lane = threadIdx.x;      // 0..63
    const int b = blockIdx.x;

    // --- gate unitaries: Rot(phi,theta,omega) = RZ(omega) RY(theta) RZ(phi)
    if (lane < NL * NQ) {
        float phi = qw[lane * 3 + 0], theta = qw[lane * 3 + 1], omega = qw[lane * 3 + 2];
        float st, ct; sincosf(0.5f * theta, &st, &ct);
        float spm, cpm; sincosf(0.5f * (phi - omega), &spm, &cpm);
        float spp, cpp; sincosf(0.5f * (phi + omega), &spp, &cpp);
        su[lane][0] =  cpp * ct; su[lane][1] = -spp * ct;   // U00
        su[lane][2] = -cpm * st; su[lane][3] = -spm * st;   // U01
        su[lane][4] =  cpm * st; su[lane][5] = -spm * st;   // U10
        su[lane][6] =  cpp * ct; su[lane][7] =  spp * ct;   // U11
    }
    __syncthreads();

    // --- load row + normalize (amplitude embedding)
    const float* hr = Hbuf + (size_t)b * DIM + (lane << 4);
    float re[16], im[16];
    {
        float4 h0 = *reinterpret_cast<const float4*>(hr + 0);
        float4 h1 = *reinterpret_cast<const float4*>(hr + 4);
        float4 h2 = *reinterpret_cast<const float4*>(hr + 8);
        float4 h3 = *reinterpret_cast<const float4*>(hr + 12);
        re[0]=h0.x; re[1]=h0.y; re[2]=h0.z; re[3]=h0.w;
        re[4]=h1.x; re[5]=h1.y; re[6]=h1.z; re[7]=h1.w;
        re[8]=h2.x; re[9]=h2.y; re[10]=h2.z; re[11]=h2.w;
        re[12]=h3.x; re[13]=h3.y; re[14]=h3.z; re[15]=h3.w;
    }
    float nrm = 0.f;
#pragma unroll
    for (int k = 0; k < 16; ++k) nrm = fmaf(re[k], re[k], nrm);
#pragma unroll
    for (int m = 1; m < 64; m <<= 1) nrm += __shfl_xor(nrm, m, 64);
    const float rn = rsqrtf(nrm);
#pragma unroll
    for (int k = 0; k < 16; ++k) { re[k] *= rn; im[k] = 0.f; }

    // --- layers
    for (int l = 0; l < NL; ++l) {
        const float* up = &su[l * NQ][0];

        // wires 0..5: lane-bit gates (shfl_xor)
#pragma unroll
        for (int w = 0; w < 6; ++w) {
            const int ml = 1 << (5 - w);
            const float4 ua = *reinterpret_cast<const float4*>(up + w * 8 + 0);
            const float4 ub = *reinterpret_cast<const float4*>(up + w * 8 + 4);
            const bool hi = (lane & ml) != 0;
            const float cmr = hi ? ub.z : ua.x;   // coeff of my amp
            const float cmi = hi ? ub.w : ua.y;
            const float cpr = hi ? ub.x : ua.z;   // coeff of partner amp
            const float cpi = hi ? ub.y : ua.w;
#pragma unroll
            for (int k = 0; k < 16; ++k) {
                const float pr = __shfl_xor(re[k], ml, 64);
                const float pi = __shfl_xor(im[k], ml, 64);
                const float ar = re[k], ai = im[k];
                re[k] = cmr * ar - cmi * ai + cpr * pr - cpi * pi;
                im[k] = cmr * ai + cmi * ar + cpr * pi + cpi * pr;
            }
        }
        // wires 6..9: register-bit gates
#pragma unroll
        for (int w = 6; w < 10; ++w) {
            const int mk = 1 << (9 - w);
            const float4 ua = *reinterpret_cast<const float4*>(up + w * 8 + 0);
            const float4 ub = *reinterpret_cast<const float4*>(up + w * 8 + 4);
#pragma unroll
            for (int k = 0; k < 16; ++k) {
                if (!(k & mk)) {
                    const int k1 = k | mk;
                    const float a0r = re[k], a0i = im[k];
                    const float a1r = re[k1], a1i = im[k1];
                    re[k]  = ua.x * a0r - ua.y * a0i + ua.z * a1r - ua.w * a1i;
                    im[k]  = ua.x * a0i + ua.y * a0r + ua.z * a1i + ua.w * a1r;
                    re[k1] = ub.x * a0r - ub.y * a0i + ub.z * a1r - ub.w * a1i;
                    im[k1] = ub.x * a0i + ub.y * a0r + ub.z * a1i + ub.w * a1r;
                }
            }
        }

        // --- CNOT ring permutation via swizzled LDS round-trip
        const int r = l + 1;                       // (l % 9) + 1
        const int jbase = perm_chain(lane << 4, r);
        const int c0 = perm_chain(1, r);
        const int c1 = perm_chain(2, r);
        const int c2 = perm_chain(4, r);
        const int c3 = perm_chain(8, r);
        const int m = (lane >> 1) & 15;
        const int wbase = lane << 4;
        __syncthreads();
#pragma unroll
        for (int k = 0; k < 16; ++k) {
            sre[wbase | (k ^ m)] = re[k];
            sim[wbase | (k ^ m)] = im[k];
        }
        __syncthreads();
#pragma unroll
        for (int k = 0; k < 16; ++k) {
            int jk = 0;
            if (k & 1) jk ^= c0;
            if (k & 2) jk ^= c1;
            if (k & 4) jk ^= c2;
            if (k & 8) jk ^= c3;
            const int j = jbase ^ jk;
            const int slot = (j & ~15) | ((j & 15) ^ ((j >> 5) & 15));
            re[k] = sre[slot];
            im[k] = sim[slot];
        }
    }

    // --- PauliZ expvals
    float ptot = 0.f, zk0 = 0.f, zk1 = 0.f, zk2 = 0.f, zk3 = 0.f;
#pragma unroll
    for (int k = 0; k < 16; ++k) {
        const float p = re[k] * re[k] + im[k] * im[k];
        ptot += p;
        zk0 += (k & 8) ? -p : p;   // wire 6 (bit 3)
        zk1 += (k & 4) ? -p : p;   // wire 7 (bit 2)
        zk2 += (k & 2) ? -p : p;   // wire 8 (bit 1)
        zk3 += (k & 1) ? -p : p;   // wire 9 (bit 0)
    }
    float z[NQ];
#pragma unroll
    for (int w = 0; w < 6; ++w)
        z[w] = ((lane >> (5 - w)) & 1) ? -ptot : ptot;
    z[6] = zk0; z[7] = zk1; z[8] = zk2; z[9] = zk3;
#pragma unroll
    for (int w = 0; w < NQ; ++w)
#pragma unroll
        for (int m2 = 1; m2 < 64; m2 <<= 1)
            z[w] += __shfl_xor(z[w], m2, 64);

    // --- post-GEMM: out[b*64 + lane]
    float o = b_post[lane];
#pragma unroll
    for (int w = 0; w < NQ; ++w)
        o = fmaf(z[w], W_post[lane * NQ + w], o);
    out[(size_t)b * OUTF + lane] = o;
}

extern "C" void kernel_launch(void* const* d_in, const int* in_sizes, int n_in,
                              void* d_out, int out_size, void* d_ws, size_t ws_size,
                              hipStream_t stream) {
    const float* x      = (const float*)d_in[0];
    const float* W_pre  = (const float*)d_in[1];
    const float* b_pre  = (const float*)d_in[2];
    const float* qw     = (const float*)d_in[3];
    const float* W_post = (const float*)d_in[4];
    const float* b_post = (const float*)d_in[5];
    float* out = (float*)d_out;
    float* h   = (float*)d_ws;   // 4096*1024 f32 = 16 MB scratch

    const int M = 4096;
    dim3 g1(M / 64, DIM / 64);
    gemm_relu_kernel<<<g1, 256, 0, stream>>>(x, W_pre, b_pre, h);
    quantum_kernel<<<M, 64, 0, stream>>>(h, qw, W_post, b_post, out);
}

// Round 3
// 64.916 us; speedup vs baseline: 2.3406x; 1.8130x over previous
//
#include <hip/hip_runtime.h>
#include <hip/hip_bf16.h>
#include <math.h>

#define NQ   10
#define DIM  1024     // 2^NQ
#define NL   4
#define INF  512
#define OUTF 64
#define MBATCH 4096

typedef _Float16 half8 __attribute__((ext_vector_type(8)));
typedef float f32x4 __attribute__((ext_vector_type(4)));

// ws layout (bytes): [0, 8M) h_f16 [4096][1024]; [8M, 12M) x_f16 [4096][512];
// [12M, 13M) w_f16 [1024][512]; [13M+512K, +1280) su[40][8] f32.
#define WS_H16  0
#define WS_X16  (8u * 1024u * 1024u)
#define WS_W16  (12u * 1024u * 1024u)
#define WS_SU   (13u * 1024u * 1024u)

// ---------------------------------------------------------------------------
// Setup: f32->f16 conversion of x and W_pre; gate unitary table su[40][8].
// Rot(phi,theta,omega) = RZ(omega) RY(theta) RZ(phi).
// ---------------------------------------------------------------------------
__global__ __launch_bounds__(256) void setup_kernel(
    const float* __restrict__ x, const float* __restrict__ w,
    const float* __restrict__ qw, _Float16* __restrict__ x16,
    _Float16* __restrict__ w16, float* __restrict__ su)
{
    const int bid = blockIdx.x;
    const int tid = threadIdx.x;
    if (bid < 1024) {               // x: 2,097,152 elems, 2048 per block
        const int base = bid * 2048 + tid * 8;
        float4 a = *reinterpret_cast<const float4*>(x + base);
        float4 b = *reinterpret_cast<const float4*>(x + base + 4);
        half8 o = {(_Float16)a.x, (_Float16)a.y, (_Float16)a.z, (_Float16)a.w,
                   (_Float16)b.x, (_Float16)b.y, (_Float16)b.z, (_Float16)b.w};
        *reinterpret_cast<half8*>(x16 + base) = o;
    } else if (bid < 1280) {        // W: 524,288 elems
        const int base = (bid - 1024) * 2048 + tid * 8;
        float4 a = *reinterpret_cast<const float4*>(w + base);
        float4 b = *reinterpret_cast<const float4*>(w + base + 4);
        half8 o = {(_Float16)a.x, (_Float16)a.y, (_Float16)a.z, (_Float16)a.w,
                   (_Float16)b.x, (_Float16)b.y, (_Float16)b.z, (_Float16)b.w};
        *reinterpret_cast<half8*>(w16 + base) = o;
    } else {                        // su
        if (tid < NL * NQ) {
            float phi = qw[tid * 3 + 0], theta = qw[tid * 3 + 1], omega = qw[tid * 3 + 2];
            float st, ct; sincosf(0.5f * theta, &st, &ct);
            float spm, cpm; sincosf(0.5f * (phi - omega), &spm, &cpm);
            float spp, cpp; sincosf(0.5f * (phi + omega), &spp, &cpp);
            float* o = su + tid * 8;
            o[0] =  cpp * ct; o[1] = -spp * ct;   // U00
            o[2] = -cpm * st; o[3] = -spm * st;   // U01
            o[4] =  cpm * st; o[5] = -spm * st;   // U10
            o[6] =  cpp * ct; o[7] =  spp * ct;   // U11
        }
    }
}

// ---------------------------------------------------------------------------
// Kernel 1: h16 = f16(relu(x @ W_pre^T + b_pre)) via mfma_f32_16x16x32_f16.
// BM=128 BN=64 BK=32, 256 threads (4 waves, 2x2 wave grid), grid 32x16.
// ---------------------------------------------------------------------------
__global__ __launch_bounds__(256) void gemm16_kernel(
    const _Float16* __restrict__ X, const _Float16* __restrict__ W,
    const float* __restrict__ bias, _Float16* __restrict__ H)
{
    constexpr int BM = 128, BN = 64, BK = 32, LDP = BK + 8;  // pad: 40 f16 = 80 B rows
    __shared__ _Float16 As[BM][LDP];
    __shared__ _Float16 Bs[BN][LDP];

    const int tid = threadIdx.x;
    const int wave = tid >> 6, lane = tid & 63;
    const int wm = wave >> 1, wn = wave & 1;
    const int l15 = lane & 15, lk = (lane >> 4) * 8;

    const int arow = tid >> 1, ahalf = tid & 1;   // A: 128 rows x 2 halves of 16
    const int brow = tid & 63, bseg = tid >> 6;   // B: 64 rows x 4 segs of 8

    const _Float16* ag = X + (size_t)(blockIdx.x * BM + arow) * INF + ahalf * 16;
    const _Float16* bg = W + (size_t)(blockIdx.y * BN + brow) * INF + bseg * 8;

    f32x4 acc[4][2] = {};

    for (int k0 = 0; k0 < INF; k0 += BK) {
        half8 av0 = *reinterpret_cast<const half8*>(ag + k0);
        half8 av1 = *reinterpret_cast<const half8*>(ag + k0 + 8);
        half8 bv  = *reinterpret_cast<const half8*>(bg + k0);
        __syncthreads();
        *reinterpret_cast<half8*>(&As[arow][ahalf * 16])     = av0;
        *reinterpret_cast<half8*>(&As[arow][ahalf * 16 + 8]) = av1;
        *reinterpret_cast<half8*>(&Bs[brow][bseg * 8])       = bv;
        __syncthreads();
        half8 bfr0 = *reinterpret_cast<const half8*>(&Bs[wn * 32 + l15][lk]);
        half8 bfr1 = *reinterpret_cast<const half8*>(&Bs[wn * 32 + 16 + l15][lk]);
#pragma unroll
        for (int mi = 0; mi < 4; ++mi) {
            half8 afr = *reinterpret_cast<const half8*>(&As[wm * 64 + mi * 16 + l15][lk]);
            acc[mi][0] = __builtin_amdgcn_mfma_f32_16x16x32_f16(afr, bfr0, acc[mi][0], 0, 0, 0);
            acc[mi][1] = __builtin_amdgcn_mfma_f32_16x16x32_f16(afr, bfr1, acc[mi][1], 0, 0, 0);
        }
    }

    const int crow0 = blockIdx.x * BM + wm * 64;
    const int ccol0 = blockIdx.y * BN + wn * 32;
#pragma unroll
    for (int ni = 0; ni < 2; ++ni) {
        const int col = ccol0 + ni * 16 + l15;
        const float bb = bias[col];
#pragma unroll
        for (int mi = 0; mi < 4; ++mi) {
#pragma unroll
            for (int r = 0; r < 4; ++r) {
                const int row = crow0 + mi * 16 + (lane >> 4) * 4 + r;
                const float o = fmaxf(acc[mi][ni][r] + bb, 0.f);
                H[(size_t)row * DIM + col] = (_Float16)o;
            }
        }
    }
}

// ---------------------------------------------------------------------------
// Cross-lane xor exchange: DPP (VALU pipe) for 1,2,8; ds_swizzle for 4,16;
// ds_bpermute for 32.
// ---------------------------------------------------------------------------
template<int ML>
__device__ __forceinline__ float lxor(float v, int bpa) {
    if constexpr (ML == 32)
        return __int_as_float(__builtin_amdgcn_ds_bpermute(bpa, __float_as_int(v)));
    else if constexpr (ML == 16)
        return __int_as_float(__builtin_amdgcn_ds_swizzle(__float_as_int(v), 0x401F));
    else if constexpr (ML == 8)
        return __int_as_float(__builtin_amdgcn_mov_dpp(__float_as_int(v), 0x128, 0xF, 0xF, false));
    else if constexpr (ML == 4)
        return __int_as_float(__builtin_amdgcn_ds_swizzle(__float_as_int(v), 0x101F));
    else if constexpr (ML == 2)
        return __int_as_float(__builtin_amdgcn_mov_dpp(__float_as_int(v), 0x4E, 0xF, 0xF, false));
    else
        return __int_as_float(__builtin_amdgcn_mov_dpp(__float_as_int(v), 0xB1, 0xF, 0xF, false));
}

__device__ __forceinline__ int perm_chain(int j, int r) {
#pragma unroll
    for (int w2 = NQ - 1; w2 >= 0; --w2) {
        const int cb = 9 - w2;
        const int tb = 9 - ((w2 + r) % NQ);
        j ^= ((j >> cb) & 1) << tb;
    }
    return j;
}

template<int W>
__device__ __forceinline__ void lane_gate(float re[16], float im[16],
                                          const float* up, int lane, int bpa) {
    constexpr int ML = 1 << (5 - W);
    const float4 ua = *reinterpret_cast<const float4*>(up + W * 8);
    const float4 ub = *reinterpret_cast<const float4*>(up + W * 8 + 4);
    const bool hi = (lane & ML) != 0;
    const float cmr = hi ? ub.z : ua.x;
    const float cmi = hi ? ub.w : ua.y;
    const float cpr = hi ? ub.x : ua.z;
    const float cpi = hi ? ub.y : ua.w;
#pragma unroll
    for (int k = 0; k < 16; ++k) {
        const float pr = lxor<ML>(re[k], bpa);
        const float pi = lxor<ML>(im[k], bpa);
        const float ar = re[k], ai = im[k];
        re[k] = cmr * ar - cmi * ai + cpr * pr - cpi * pi;
        im[k] = cmr * ai + cmi * ar + cpr * pi + cpi * pr;
    }
}

// ---------------------------------------------------------------------------
// Kernel 2: one wave per batch row; 16 amps/thread, i = (lane<<4) | k.
// ---------------------------------------------------------------------------
__global__ __launch_bounds__(64) void quantum_kernel(
    const _Float16* __restrict__ Hbuf, const float* __restrict__ sug,
    const float* __restrict__ W_post, const float* __restrict__ b_post,
    float* __restrict__ out)
{
    __shared__ float sre[DIM];
    __shared__ float sim[DIM];

    const int lane = threadIdx.x;      // 0..63
    const int b = blockIdx.x;
    const int bpa = (lane ^ 32) << 2;  // bpermute byte addr for xor-32

    // --- load row (f16) + normalize
    const _Float16* hr = Hbuf + (size_t)b * DIM + (lane << 4);
    float re[16], im[16];
    {
        half8 h0 = *reinterpret_cast<const half8*>(hr);
        half8 h1 = *reinterpret_cast<const half8*>(hr + 8);
#pragma unroll
        for (int j = 0; j < 8; ++j) { re[j] = (float)h0[j]; re[8 + j] = (float)h1[j]; }
    }
    float nrm = 0.f;
#pragma unroll
    for (int k = 0; k < 16; ++k) nrm = fmaf(re[k], re[k], nrm);
#pragma unroll
    for (int m = 1; m < 64; m <<= 1) nrm += __shfl_xor(nrm, m, 64);
    const float rn = rsqrtf(nrm);
#pragma unroll
    for (int k = 0; k < 16; ++k) { re[k] *= rn; im[k] = 0.f; }

    // --- layers
    for (int l = 0; l < NL; ++l) {
        const float* up = sug + l * NQ * 8;

        // wires 0..5: lane-bit gates
        lane_gate<0>(re, im, up, lane, bpa);
        lane_gate<1>(re, im, up, lane, bpa);
        lane_gate<2>(re, im, up, lane, bpa);
        lane_gate<3>(re, im, up, lane, bpa);
        lane_gate<4>(re, im, up, lane, bpa);
        lane_gate<5>(re, im, up, lane, bpa);

        // wires 6..9: register-bit gates
#pragma unroll
        for (int w = 6; w < 10; ++w) {
            const int mk = 1 << (9 - w);
            const float4 ua = *reinterpret_cast<const float4*>(up + w * 8);
            const float4 ub = *reinterpret_cast<const float4*>(up + w * 8 + 4);
#pragma unroll
            for (int k = 0; k < 16; ++k) {
                if (!(k & mk)) {
                    const int k1 = k | mk;
                    const float a0r = re[k], a0i = im[k];
                    const float a1r = re[k1], a1i = im[k1];
                    re[k]  = ua.x * a0r - ua.y * a0i + ua.z * a1r - ua.w * a1i;
                    im[k]  = ua.x * a0i + ua.y * a0r + ua.z * a1i + ua.w * a1r;
                    re[k1] = ub.x * a0r - ub.y * a0i + ub.z * a1r - ub.w * a1i;
                    im[k1] = ub.x * a0i + ub.y * a0r + ub.z * a1i + ub.w * a1r;
                }
            }
        }

        // --- CNOT ring permutation via swizzled LDS round-trip
        const int r = l + 1;
        const int jbase = perm_chain(lane << 4, r);
        const int c0 = perm_chain(1, r);
        const int c1 = perm_chain(2, r);
        const int c2 = perm_chain(4, r);
        const int c3 = perm_chain(8, r);
        const int m = (lane >> 1) & 15;
        const int wbase = lane << 4;
        __syncthreads();
#pragma unroll
        for (int k = 0; k < 16; ++k) {
            sre[wbase | (k ^ m)] = re[k];
            sim[wbase | (k ^ m)] = im[k];
        }
        __syncthreads();
#pragma unroll
        for (int k = 0; k < 16; ++k) {
            int jk = 0;
            if (k & 1) jk ^= c0;
            if (k & 2) jk ^= c1;
            if (k & 4) jk ^= c2;
            if (k & 8) jk ^= c3;
            const int j = jbase ^ jk;
            const int slot = (j & ~15) | ((j & 15) ^ ((j >> 5) & 15));
            re[k] = sre[slot];
            im[k] = sim[slot];
        }
    }

    // --- PauliZ expvals
    float ptot = 0.f, zk0 = 0.f, zk1 = 0.f, zk2 = 0.f, zk3 = 0.f;
#pragma unroll
    for (int k = 0; k < 16; ++k) {
        const float p = re[k] * re[k] + im[k] * im[k];
        ptot += p;
        zk0 += (k & 8) ? -p : p;
        zk1 += (k & 4) ? -p : p;
        zk2 += (k & 2) ? -p : p;
        zk3 += (k & 1) ? -p : p;
    }
    float z[NQ];
#pragma unroll
    for (int w = 0; w < 6; ++w)
        z[w] = ((lane >> (5 - w)) & 1) ? -ptot : ptot;
    z[6] = zk0; z[7] = zk1; z[8] = zk2; z[9] = zk3;
#pragma unroll
    for (int w = 0; w < NQ; ++w)
#pragma unroll
        for (int m2 = 1; m2 < 64; m2 <<= 1)
            z[w] += __shfl_xor(z[w], m2, 64);

    // --- post-GEMM: out[b*64 + lane]
    float o = b_post[lane];
#pragma unroll
    for (int w = 0; w < NQ; ++w)
        o = fmaf(z[w], W_post[lane * NQ + w], o);
    out[(size_t)b * OUTF + lane] = o;
}

extern "C" void kernel_launch(void* const* d_in, const int* in_sizes, int n_in,
                              void* d_out, int out_size, void* d_ws, size_t ws_size,
                              hipStream_t stream) {
    const float* x      = (const float*)d_in[0];
    const float* W_pre  = (const float*)d_in[1];
    const float* b_pre  = (const float*)d_in[2];
    const float* qw     = (const float*)d_in[3];
    const float* W_post = (const float*)d_in[4];
    const float* b_post = (const float*)d_in[5];
    float* out = (float*)d_out;

    char* ws = (char*)d_ws;
    _Float16* h16 = (_Float16*)(ws + WS_H16);
    _Float16* x16 = (_Float16*)(ws + WS_X16);
    _Float16* w16 = (_Float16*)(ws + WS_W16);
    float*    su  = (float*)   (ws + WS_SU);

    setup_kernel<<<1281, 256, 0, stream>>>(x, W_pre, qw, x16, w16, su);
    dim3 g1(MBATCH / 128, DIM / 64);
    gemm16_kernel<<<g1, 256, 0, stream>>>(x16, w16, b_pre, h16);
    quantum_kernel<<<MBATCH, 64, 0, stream>>>(h16, su, W_post, b_post, out);
}

// Round 4
// 62.260 us; speedup vs baseline: 2.4404x; 1.0427x over previous
//
#include <hip/hip_runtime.h>
#include <hip/hip_bf16.h>
#include <math.h>

#define NQ   10
#define DIM  1024     // 2^NQ
#define NL   4
#define INF  512
#define OUTF 64
#define MBATCH 4096

typedef _Float16 half8 __attribute__((ext_vector_type(8)));
typedef float f32x4 __attribute__((ext_vector_type(4)));
typedef float f32x2 __attribute__((ext_vector_type(2)));

// ws layout (bytes)
#define WS_H16  0
#define WS_X16  (8u * 1024u * 1024u)
#define WS_W16  (12u * 1024u * 1024u)
#define WS_SU   (13u * 1024u * 1024u)

// ===========================================================================
// Compile-time GF(2) layout tracking for the CNOT ring permutations.
// f_l = perm_chain(., r=l+1) (verified rounds 1-3): psi_new[i] = psi_old[f_l(i)].
// Layout invariant: psi[i] = P[sigma(i)]; after layer l perm: sigma' = sigma∘f_l.
// ===========================================================================
constexpr int fstep(int j, int r) {
    for (int w2 = NQ - 1; w2 >= 0; --w2) {
        const int cb = 9 - w2;
        const int tb = 9 - ((w2 + r) % NQ);
        j ^= ((j >> cb) & 1) << tb;
    }
    return j;
}
constexpr int ifstep(int j, int r) {   // inverse: self-inverse steps, reverse order
    for (int w2 = 0; w2 < NQ; ++w2) {
        const int cb = 9 - w2;
        const int tb = 9 - ((w2 + r) % NQ);
        j ^= ((j >> cb) & 1) << tb;
    }
    return j;
}
// sigma_l(x) = f_0(f_1(...f_{l-1}(x)))
constexpr int sigma_fwd(int l, int x) {
    for (int t = l - 1; t >= 0; --t) x = fstep(x, t + 1);
    return x;
}
// sigma_l^{-1}(s) = f_{l-1}^{-1}(...(f_0^{-1}(s))): apply f_0^{-1} first
constexpr int sigma_inv(int l, int s) {
    for (int t = 0; t < l; ++t) s = ifstep(s, t + 1);
    return s;
}
constexpr int gate_m(int l, int b) { return sigma_fwd(l, 1 << b); }
constexpr int gate_g(int l, int b) {
    int g = 0;
    for (int j = 0; j < NQ; ++j)
        if ((sigma_inv(l, 1 << j) >> b) & 1) g |= 1 << j;
    return g;
}
struct QM { int v[NQ]; };
constexpr QM make_qm() {
    QM q{};
    for (int w = 0; w < NQ; ++w) {
        const int B = 9 - w;
        int m = 0;
        for (int j = 0; j < NQ; ++j)
            if ((sigma_inv(NL, 1 << j) >> B) & 1) m |= 1 << j;
        q.v[w] = m;
    }
    return q;
}
constexpr QM QMASKS = make_qm();

// ===========================================================================
// Setup: f32->f16 of x and W_pre; gate unitary table su[40][8].
// ===========================================================================
__global__ __launch_bounds__(256) void setup_kernel(
    const float* __restrict__ x, const float* __restrict__ w,
    const float* __restrict__ qw, _Float16* __restrict__ x16,
    _Float16* __restrict__ w16, float* __restrict__ su)
{
    const int bid = blockIdx.x;
    const int tid = threadIdx.x;
    if (bid < 1024) {
        const int base = bid * 2048 + tid * 8;
        float4 a = *reinterpret_cast<const float4*>(x + base);
        float4 b = *reinterpret_cast<const float4*>(x + base + 4);
        half8 o = {(_Float16)a.x, (_Float16)a.y, (_Float16)a.z, (_Float16)a.w,
                   (_Float16)b.x, (_Float16)b.y, (_Float16)b.z, (_Float16)b.w};
        *reinterpret_cast<half8*>(x16 + base) = o;
    } else if (bid < 1280) {
        const int base = (bid - 1024) * 2048 + tid * 8;
        float4 a = *reinterpret_cast<const float4*>(w + base);
        float4 b = *reinterpret_cast<const float4*>(w + base + 4);
        half8 o = {(_Float16)a.x, (_Float16)a.y, (_Float16)a.z, (_Float16)a.w,
                   (_Float16)b.x, (_Float16)b.y, (_Float16)b.z, (_Float16)b.w};
        *reinterpret_cast<half8*>(w16 + base) = o;
    } else {
        if (tid < NL * NQ) {
            float phi = qw[tid * 3 + 0], theta = qw[tid * 3 + 1], omega = qw[tid * 3 + 2];
            float st, ct; sincosf(0.5f * theta, &st, &ct);
            float spm, cpm; sincosf(0.5f * (phi - omega), &spm, &cpm);
            float spp, cpp; sincosf(0.5f * (phi + omega), &spp, &cpp);
            float* o = su + tid * 8;
            o[0] =  cpp * ct; o[1] = -spp * ct;   // U00
            o[2] = -cpm * st; o[3] = -spm * st;   // U01
            o[4] =  cpm * st; o[5] = -spm * st;   // U10
            o[6] =  cpp * ct; o[7] =  spp * ct;   // U11
        }
    }
}

// ===========================================================================
// Kernel 1: h16 = f16(relu(x @ W_pre^T + b_pre)) via mfma_f32_16x16x32_f16.
// ===========================================================================
__global__ __launch_bounds__(256) void gemm16_kernel(
    const _Float16* __restrict__ X, const _Float16* __restrict__ W,
    const float* __restrict__ bias, _Float16* __restrict__ H)
{
    constexpr int BM = 128, BN = 64, BK = 32, LDP = BK + 8;
    __shared__ _Float16 As[BM][LDP];
    __shared__ _Float16 Bs[BN][LDP];

    const int tid = threadIdx.x;
    const int wave = tid >> 6, lane = tid & 63;
    const int wm = wave >> 1, wn = wave & 1;
    const int l15 = lane & 15, lk = (lane >> 4) * 8;

    const int arow = tid >> 1, ahalf = tid & 1;
    const int brow = tid & 63, bseg = tid >> 6;

    const _Float16* ag = X + (size_t)(blockIdx.x * BM + arow) * INF + ahalf * 16;
    const _Float16* bg = W + (size_t)(blockIdx.y * BN + brow) * INF + bseg * 8;

    f32x4 acc[4][2] = {};

    for (int k0 = 0; k0 < INF; k0 += BK) {
        half8 av0 = *reinterpret_cast<const half8*>(ag + k0);
        half8 av1 = *reinterpret_cast<const half8*>(ag + k0 + 8);
        half8 bv  = *reinterpret_cast<const half8*>(bg + k0);
        __syncthreads();
        *reinterpret_cast<half8*>(&As[arow][ahalf * 16])     = av0;
        *reinterpret_cast<half8*>(&As[arow][ahalf * 16 + 8]) = av1;
        *reinterpret_cast<half8*>(&Bs[brow][bseg * 8])       = bv;
        __syncthreads();
        half8 bfr0 = *reinterpret_cast<const half8*>(&Bs[wn * 32 + l15][lk]);
        half8 bfr1 = *reinterpret_cast<const half8*>(&Bs[wn * 32 + 16 + l15][lk]);
#pragma unroll
        for (int mi = 0; mi < 4; ++mi) {
            half8 afr = *reinterpret_cast<const half8*>(&As[wm * 64 + mi * 16 + l15][lk]);
            acc[mi][0] = __builtin_amdgcn_mfma_f32_16x16x32_f16(afr, bfr0, acc[mi][0], 0, 0, 0);
            acc[mi][1] = __builtin_amdgcn_mfma_f32_16x16x32_f16(afr, bfr1, acc[mi][1], 0, 0, 0);
        }
    }

    const int crow0 = blockIdx.x * BM + wm * 64;
    const int ccol0 = blockIdx.y * BN + wn * 32;
#pragma unroll
    for (int ni = 0; ni < 2; ++ni) {
        const int col = ccol0 + ni * 16 + l15;
        const float bb = bias[col];
#pragma unroll
        for (int mi = 0; mi < 4; ++mi) {
#pragma unroll
            for (int r = 0; r < 4; ++r) {
                const int row = crow0 + mi * 16 + (lane >> 4) * 4 + r;
                const float o = fmaxf(acc[mi][ni][r] + bb, 0.f);
                H[(size_t)row * DIM + col] = (_Float16)o;
            }
        }
    }
}

// ===========================================================================
// Cross-lane xor exchange, compile-time mask dispatch.
// ===========================================================================
template<int MHI>
__device__ __forceinline__ float lx(float v, int lane) {
    if constexpr (MHI == 0)
        return v;
    else if constexpr (MHI == 1)
        return __int_as_float(__builtin_amdgcn_mov_dpp(__float_as_int(v), 0xB1, 0xF, 0xF, false));
    else if constexpr (MHI == 2)
        return __int_as_float(__builtin_amdgcn_mov_dpp(__float_as_int(v), 0x4E, 0xF, 0xF, false));
    else if constexpr (MHI == 3)
        return __int_as_float(__builtin_amdgcn_mov_dpp(__float_as_int(v), 0x1B, 0xF, 0xF, false));
    else if constexpr (MHI == 8)
        return __int_as_float(__builtin_amdgcn_mov_dpp(__float_as_int(v), 0x128, 0xF, 0xF, false));
    else if constexpr (MHI < 32)
        return __int_as_float(__builtin_amdgcn_ds_swizzle(__float_as_int(v), 0x1F | (MHI << 10)));
    else
        return __int_as_float(__builtin_amdgcn_ds_bpermute((lane ^ MHI) << 2, __float_as_int(v)));
}

// ===========================================================================
// One gate (layer L, wire W) under tracked layout. State: rr/ii[8] f32x2
// (amp k: k even -> .x of [k/2]). Physical butterfly mask m, hi-parity mask g.
// ===========================================================================
template<int L, int W>
__device__ __forceinline__ void apply_gate(f32x2 rr[8], f32x2 ii[8],
                                           const float* __restrict__ su, int lane)
{
    constexpr int b   = 9 - W;
    constexpr int m   = gate_m(L, b);
    constexpr int g   = gate_g(L, b);
    constexpr int MHI = m >> 4, MLO = m & 15;
    constexpr int GHI = g >> 4, GLO = g & 15;

    const float4 ua = *reinterpret_cast<const float4*>(su + (L * NQ + W) * 8);
    const float4 ub = *reinterpret_cast<const float4*>(su + (L * NQ + W) * 8 + 4);
    const bool hl = __builtin_popcount(lane & GHI) & 1;

    // coefficient sets by hk = parity(k & GLO):  hi = hl ^ hk
    const float cmr0 = hl ? ub.z : ua.x, cmi0 = hl ? ub.w : ua.y;
    const float cpr0 = hl ? ub.x : ua.z, cpi0 = hl ? ub.y : ua.w;
    const float cmr1 = hl ? ua.x : ub.z, cmi1 = hl ? ua.y : ub.w;
    const float cpr1 = hl ? ua.z : ub.x, cpi1 = hl ? ua.w : ub.y;

    // snapshot partner amplitudes (lockstep wave => reads see pre-gate values)
    float pr[16], pi[16];
#pragma unroll
    for (int k = 0; k < 16; ++k) {
        const int kp = k ^ MLO;
        const float vr = (kp & 1) ? rr[kp >> 1].y : rr[kp >> 1].x;
        const float vi = (kp & 1) ? ii[kp >> 1].y : ii[kp >> 1].x;
        pr[k] = lx<MHI>(vr, lane);
        pi[k] = lx<MHI>(vi, lane);
    }
#pragma unroll
    for (int j = 0; j < 8; ++j) {
        const int k0 = 2 * j, k1 = 2 * j + 1;
        const int h0 = __builtin_popcount(k0 & GLO) & 1;   // folds after unroll
        const int h1 = __builtin_popcount(k1 & GLO) & 1;
        f32x2 CMR, CMI, CPR, CPI, PR, PI;
        CMR.x = h0 ? cmr1 : cmr0;  CMR.y = h1 ? cmr1 : cmr0;
        CMI.x = h0 ? cmi1 : cmi0;  CMI.y = h1 ? cmi1 : cmi0;
        CPR.x = h0 ? cpr1 : cpr0;  CPR.y = h1 ? cpr1 : cpr0;
        CPI.x = h0 ? cpi1 : cpi0;  CPI.y = h1 ? cpi1 : cpi0;
        PR.x = pr[k0]; PR.y = pr[k1];
        PI.x = pi[k0]; PI.y = pi[k1];
        const f32x2 R = rr[j], I = ii[j];
        rr[j] = R * CMR - I * CMI + PR * CPR - PI * CPI;
        ii[j] = I * CMR + R * CMI + PI * CPR + PR * CPI;
    }
}

template<int L>
__device__ __forceinline__ void apply_layer(f32x2 rr[8], f32x2 ii[8],
                                            const float* __restrict__ su, int lane)
{
    apply_gate<L, 0>(rr, ii, su, lane);
    apply_gate<L, 1>(rr, ii, su, lane);
    apply_gate<L, 2>(rr, ii, su, lane);
    apply_gate<L, 3>(rr, ii, su, lane);
    apply_gate<L, 4>(rr, ii, su, lane);
    apply_gate<L, 5>(rr, ii, su, lane);
    apply_gate<L, 6>(rr, ii, su, lane);
    apply_gate<L, 7>(rr, ii, su, lane);
    apply_gate<L, 8>(rr, ii, su, lane);
    apply_gate<L, 9>(rr, ii, su, lane);
}

// ===========================================================================
// Kernel 2: one wave per batch row, 4 rows per 256-thread block. No LDS,
// no barriers. Unnormalized evolution; 1/||h||^2 folded into z.
// ===========================================================================
__global__ __launch_bounds__(256) void quantum_kernel(
    const _Float16* __restrict__ Hbuf, const float* __restrict__ sug,
    const float* __restrict__ W_post, const float* __restrict__ b_post,
    float* __restrict__ out)
{
    const int lane = threadIdx.x;                       // 0..63
    const int row  = blockIdx.x * 4 + threadIdx.y;      // batch row

    // --- load row (f16); amp index i = (lane<<4) | k
    const _Float16* hr = Hbuf + (size_t)row * DIM + (lane << 4);
    f32x2 rr[8], ii[8];
    {
        half8 h0 = *reinterpret_cast<const half8*>(hr);
        half8 h1 = *reinterpret_cast<const half8*>(hr + 8);
#pragma unroll
        for (int j = 0; j < 4; ++j) {
            rr[j].x     = (float)h0[2 * j];     rr[j].y     = (float)h0[2 * j + 1];
            rr[j + 4].x = (float)h1[2 * j];     rr[j + 4].y = (float)h1[2 * j + 1];
            ii[j]     = f32x2{0.f, 0.f};
            ii[j + 4] = f32x2{0.f, 0.f};
        }
    }
    f32x2 n2 = f32x2{0.f, 0.f};
#pragma unroll
    for (int j = 0; j < 8; ++j) n2 += rr[j] * rr[j];
    float nrm = n2.x + n2.y;
#pragma unroll
    for (int m2 = 1; m2 < 64; m2 <<= 1) nrm += __shfl_xor(nrm, m2, 64);
    const float inv_nrm = 1.0f / nrm;   // ||h||^2

    // --- circuit (layout-tracked; permutations are free)
    apply_layer<0>(rr, ii, sug, lane);
    apply_layer<1>(rr, ii, sug, lane);
    apply_layer<2>(rr, ii, sug, lane);
    apply_layer<3>(rr, ii, sug, lane);

    // --- probabilities
    f32x2 P[8];
#pragma unroll
    for (int j = 0; j < 8; ++j) P[j] = rr[j] * rr[j] + ii[j] * ii[j];

    // --- PauliZ expvals with layout-adjusted sign masks
    float z[NQ];
#pragma unroll
    for (int w = 0; w < NQ; ++w) {
        const int q = QMASKS.v[w];
        const int qhi = q >> 4, qlo = q & 15;
        float zl = 0.f;
#pragma unroll
        for (int j = 0; j < 8; ++j) {
            const float s0 = (__builtin_popcount((2 * j) & qlo) & 1) ? -1.f : 1.f;
            const float s1 = (__builtin_popcount((2 * j + 1) & qlo) & 1) ? -1.f : 1.f;
            zl += s0 * P[j].x;
            zl += s1 * P[j].y;
        }
        if (__builtin_popcount(lane & qhi) & 1) zl = -zl;
#pragma unroll
        for (int m2 = 1; m2 < 64; m2 <<= 1) zl += __shfl_xor(zl, m2, 64);
        z[w] = zl * inv_nrm;
    }

    // --- post-GEMM: out[row*64 + lane]
    float o = b_post[lane];
#pragma unroll
    for (int w = 0; w < NQ; ++w)
        o = fmaf(z[w], W_post[lane * NQ + w], o);
    out[(size_t)row * OUTF + lane] = o;
}

extern "C" void kernel_launch(void* const* d_in, const int* in_sizes, int n_in,
                              void* d_out, int out_size, void* d_ws, size_t ws_size,
                              hipStream_t stream) {
    const float* x      = (const float*)d_in[0];
    const float* W_pre  = (const float*)d_in[1];
    const float* b_pre  = (const float*)d_in[2];
    const float* qw     = (const float*)d_in[3];
    const float* W_post = (const float*)d_in[4];
    const float* b_post = (const float*)d_in[5];
    float* out = (float*)d_out;

    char* ws = (char*)d_ws;
    _Float16* h16 = (_Float16*)(ws + WS_H16);
    _Float16* x16 = (_Float16*)(ws + WS_X16);
    _Float16* w16 = (_Float16*)(ws + WS_W16);
    float*    su  = (float*)   (ws + WS_SU);

    setup_kernel<<<1281, 256, 0, stream>>>(x, W_pre, qw, x16, w16, su);
    dim3 g1(MBATCH / 128, DIM / 64);
    gemm16_kernel<<<g1, 256, 0, stream>>>(x16, w16, b_pre, h16);
    quantum_kernel<<<MBATCH / 4, dim3(64, 4), 0, stream>>>(h16, su, W_post, b_post, out);
}